// Round 2
// baseline (363.060 us; speedup 1.0000x reference)
//
#include <hip/hip_runtime.h>
#include <hip/hip_bf16.h>
#include <stdint.h>

// Problem: out = x_norm + dropout(relu(LN(x) @ W1) @ W2), B=4,S=2048,D=2048
#define M_DIM 8192   // B*S
#define N_DIM 2048
#define K_DIM 2048

typedef __bf16 bf16x8_t __attribute__((ext_vector_type(8)));
typedef float f32x4_t __attribute__((ext_vector_type(4)));

// ---------------- threefry2x32, JAX partitionable path, key=(0,1) -------------
// bits(j) = o0^o1 of threefry2x32(key=(0,1), ctr=(0, j)); keep iff bits < 0xC0000000.
// Verified round 1: absmax 0.0625 -> mask exact.
__device__ __forceinline__ unsigned tf_rotl(unsigned x, int r) {
  return (x << r) | (x >> (32 - r));
}
__device__ __forceinline__ unsigned threefry_mask_bits(unsigned ctr) {
  unsigned x0 = 0u, x1 = ctr;
  const unsigned ks0 = 0u, ks1 = 1u, ks2 = 0x1BD11BDBu;
  x0 += ks0; x1 += ks1;
#define TFR(r) { x0 += x1; x1 = tf_rotl(x1, (r)); x1 ^= x0; }
  TFR(13) TFR(15) TFR(26) TFR(6)
  x0 += ks1; x1 += ks2 + 1u;
  TFR(17) TFR(29) TFR(16) TFR(24)
  x0 += ks2; x1 += ks0 + 2u;
  TFR(13) TFR(15) TFR(26) TFR(6)
  x0 += ks0; x1 += ks1 + 3u;
  TFR(17) TFR(29) TFR(16) TFR(24)
  x0 += ks1; x1 += ks2 + 4u;
  TFR(13) TFR(15) TFR(26) TFR(6)
  x0 += ks2; x1 += ks0 + 5u;
#undef TFR
  return x0 ^ x1;
}

// ---------------- async global->LDS, 16B per lane -----------------------------
__device__ __forceinline__ void gload_lds16(const __hip_bfloat16* g, unsigned short* l) {
  __builtin_amdgcn_global_load_lds(
      (const __attribute__((address_space(1))) unsigned int*)g,
      (__attribute__((address_space(3))) unsigned int*)l,
      16, 0, 0);
}

// ---------------- W [K][N] fp32 -> Wt [N][K] bf16 -----------------------------
__global__ __launch_bounds__(256) void wt_kernel(
    const float* __restrict__ W1, const float* __restrict__ W2,
    __hip_bfloat16* __restrict__ W1t, __hip_bfloat16* __restrict__ W2t) {
  __shared__ float tile[32][33];
  const float* src = blockIdx.z ? W2 : W1;
  __hip_bfloat16* dst = blockIdx.z ? W2t : W1t;
  int x = blockIdx.x * 32 + threadIdx.x;
  int y = blockIdx.y * 32 + threadIdx.y;
#pragma unroll
  for (int i = 0; i < 32; i += 8)
    tile[threadIdx.y + i][threadIdx.x] = src[(size_t)(y + i) * N_DIM + x];
  __syncthreads();
  int xo = blockIdx.y * 32 + threadIdx.x;
  int yo = blockIdx.x * 32 + threadIdx.y;
#pragma unroll
  for (int i = 0; i < 32; i += 8)
    dst[(size_t)(yo + i) * K_DIM + xo] = __float2bfloat16(tile[threadIdx.x][threadIdx.y + i]);
}

// ---------------- LayerNorm (no affine) -> bf16 -------------------------------
__global__ __launch_bounds__(256) void ln_kernel(const float* __restrict__ X,
                                                 __hip_bfloat16* __restrict__ Xn) {
  const int row = blockIdx.x;
  const float4* xv = (const float4*)(X + (size_t)row * K_DIM);
  float4 v0 = xv[threadIdx.x];
  float4 v1 = xv[threadIdx.x + 256];
  float s  = v0.x + v0.y + v0.z + v0.w + v1.x + v1.y + v1.z + v1.w;
  float ss = v0.x*v0.x + v0.y*v0.y + v0.z*v0.z + v0.w*v0.w
           + v1.x*v1.x + v1.y*v1.y + v1.z*v1.z + v1.w*v1.w;
#pragma unroll
  for (int off = 32; off > 0; off >>= 1) {
    s  += __shfl_xor(s, off);
    ss += __shfl_xor(ss, off);
  }
  __shared__ float rs[4], rss[4];
  const int wave = threadIdx.x >> 6;
  if ((threadIdx.x & 63) == 0) { rs[wave] = s; rss[wave] = ss; }
  __syncthreads();
  float S  = rs[0] + rs[1] + rs[2] + rs[3];
  float SS = rss[0] + rss[1] + rss[2] + rss[3];
  float mean = S * (1.0f / 2048.0f);
  float var  = SS * (1.0f / 2048.0f) - mean * mean;
  float rstd = 1.0f / sqrtf(var + 1e-6f);
  float vv[8] = {v0.x, v0.y, v0.z, v0.w, v1.x, v1.y, v1.z, v1.w};
  unsigned short o[8];
#pragma unroll
  for (int i = 0; i < 8; i++) {
    __hip_bfloat16 b = __float2bfloat16((vv[i] - mean) * rstd);
    o[i] = *(unsigned short*)&b;
  }
  ushort4* dst = (ushort4*)(Xn + (size_t)row * K_DIM);
  dst[threadIdx.x]       = make_ushort4(o[0], o[1], o[2], o[3]);
  dst[threadIdx.x + 256] = make_ushort4(o[4], o[5], o[6], o[7]);
}

// ---------------- 128x128 MFMA GEMM, double-buffered single-barrier K-loop ----
// A[M][K], Bt[N][K] bf16. EPI=0: H=relu(A@B)->bf16. EPI=1: out=Xn+dropout/0.75.
// Pipeline: barrier publishes buf[k]; prefetch k+1 issued AFTER that barrier so
// it is in flight during buf[k]'s ds_read+MFMA; next barrier's vmcnt(0) drain
// pays only (latency - compute). One barrier per K-iter.
template <int EPI>
__global__ __launch_bounds__(256) void gemm128(
    const __hip_bfloat16* __restrict__ A,
    const __hip_bfloat16* __restrict__ Bt,
    const __hip_bfloat16* __restrict__ Xn,   // EPI=1 residual
    __hip_bfloat16* __restrict__ Hout,       // EPI=0 output
    float* __restrict__ Fout) {              // EPI=1 output
  __shared__ unsigned short As[2][128 * 32];
  __shared__ unsigned short Bs[2][128 * 32];
  const int tid  = threadIdx.x;
  const int lane = tid & 63;
  const int wave = tid >> 6;
  const int wm = wave >> 1, wn = wave & 1;
  // grid: x walks M (64 tiles, fastest) -> consecutive blocks share the B panel
  // (512 KB) which stays hot in each XCD's 4 MB L2.
  const int mBase = blockIdx.x * 128;
  const int nBase = blockIdx.y * 128;

  f32x4_t acc[4][4];
#pragma unroll
  for (int i = 0; i < 4; i++)
#pragma unroll
    for (int j = 0; j < 4; j++) acc[i][j] = (f32x4_t){0.f, 0.f, 0.f, 0.f};

  const int r4 = lane >> 2;
  const int c4 = (lane & 3) << 3;
  const __hip_bfloat16* a0 = A  + (size_t)(mBase + 16 * wave       + r4) * K_DIM + c4;
  const __hip_bfloat16* a1 = A  + (size_t)(mBase + 16 * (wave + 4) + r4) * K_DIM + c4;
  const __hip_bfloat16* b0 = Bt + (size_t)(nBase + 16 * wave       + r4) * K_DIM + c4;
  const __hip_bfloat16* b1 = Bt + (size_t)(nBase + 16 * (wave + 4) + r4) * K_DIM + c4;
  const int sOff0 = (16 * wave) * 32;
  const int sOff1 = (16 * (wave + 4)) * 32;

  const int fr = lane & 15;
  const int fq = lane >> 4;
  const int rdOffA = (wm * 64 + fr) * 32 + fq * 8;
  const int rdOffB = (wn * 64 + fr) * 32 + fq * 8;

#define STAGE(buf, k0)                              \
  {                                                 \
    gload_lds16(a0 + (k0), &As[buf][sOff0]);        \
    gload_lds16(a1 + (k0), &As[buf][sOff1]);        \
    gload_lds16(b0 + (k0), &Bs[buf][sOff0]);        \
    gload_lds16(b1 + (k0), &Bs[buf][sOff1]);        \
  }

#define COMPUTE(buf)                                                            \
  {                                                                             \
    bf16x8_t af[4], bfr[4];                                                     \
    _Pragma("unroll")                                                           \
    for (int i = 0; i < 4; i++) af[i]  = *(const bf16x8_t*)(&As[buf][rdOffA] + i * 16 * 32); \
    _Pragma("unroll")                                                           \
    for (int i = 0; i < 4; i++) bfr[i] = *(const bf16x8_t*)(&Bs[buf][rdOffB] + i * 16 * 32); \
    _Pragma("unroll")                                                           \
    for (int mi = 0; mi < 4; mi++)                                              \
      _Pragma("unroll")                                                         \
      for (int ni = 0; ni < 4; ni++)                                            \
        acc[mi][ni] = __builtin_amdgcn_mfma_f32_16x16x32_bf16(af[mi], bfr[ni], acc[mi][ni], 0, 0, 0); \
  }

  STAGE(0, 0)
  for (int k0 = 0; k0 < K_DIM; k0 += 64) {
    __syncthreads();                       // publish buf0 (k0)
    if (k0 + 32 < K_DIM) STAGE(1, k0 + 32) // in flight during buf0 compute
    COMPUTE(0)
    __syncthreads();                       // publish buf1 (k0+32)
    if (k0 + 64 < K_DIM) STAGE(0, k0 + 64) // in flight during buf1 compute
    COMPUTE(1)
  }
#undef STAGE
#undef COMPUTE

  // epilogue: D row = fq*4 + reg, col = fr (m89-verified C/D layout)
  const int mRow = mBase + wm * 64;
  const int nCol = nBase + wn * 64;
#pragma unroll
  for (int mi = 0; mi < 4; mi++) {
#pragma unroll
    for (int ni = 0; ni < 4; ni++) {
      const int n  = nCol + ni * 16 + fr;
      const int m0 = mRow + mi * 16 + fq * 4;
#pragma unroll
      for (int r = 0; r < 4; r++) {
        float v = acc[mi][ni][r];
        size_t j = (size_t)(m0 + r) * N_DIM + n;
        if (EPI == 0) {
          Hout[j] = __float2bfloat16(fmaxf(v, 0.0f));
        } else {
          unsigned bits = threefry_mask_bits((unsigned)j);
          float y  = (bits < 0xC0000000u) ? v * (1.0f / 0.75f) : 0.0f;
          Fout[j]  = __bfloat162float(Xn[j]) + y;
        }
      }
    }
  }
}

extern "C" void kernel_launch(void* const* d_in, const int* in_sizes, int n_in,
                              void* d_out, int out_size, void* d_ws, size_t ws_size,
                              hipStream_t stream) {
  (void)in_sizes; (void)n_in; (void)out_size; (void)ws_size;
  const float* X  = (const float*)d_in[0];
  const float* W1 = (const float*)d_in[1];
  const float* W2 = (const float*)d_in[2];
  float* out = (float*)d_out;

  unsigned char* ws = (unsigned char*)d_ws;
  __hip_bfloat16* Xn  = (__hip_bfloat16*)(ws);                       // 32 MB
  __hip_bfloat16* H   = (__hip_bfloat16*)(ws + ((size_t)32 << 20));  // 32 MB
  __hip_bfloat16* W1t = (__hip_bfloat16*)(ws + ((size_t)64 << 20));  //  8 MB
  __hip_bfloat16* W2t = (__hip_bfloat16*)(ws + ((size_t)72 << 20));  //  8 MB

  wt_kernel<<<dim3(64, 64, 2), dim3(32, 8, 1), 0, stream>>>(W1, W2, W1t, W2t);
  ln_kernel<<<M_DIM, 256, 0, stream>>>(X, Xn);
  gemm128<0><<<dim3(M_DIM / 128, N_DIM / 128), 256, 0, stream>>>(Xn, W1t, nullptr, H, nullptr);
  gemm128<1><<<dim3(M_DIM / 128, N_DIM / 128), 256, 0, stream>>>(H, W2t, Xn, nullptr, out);
}

// Round 3
// 319.752 us; speedup vs baseline: 1.1354x; 1.1354x over previous
//
#include <hip/hip_runtime.h>
#include <hip/hip_bf16.h>
#include <stdint.h>

// Problem: out = x_norm + dropout(relu(LN(x) @ W1) @ W2), B=4,S=2048,D=2048
#define M_DIM 8192   // B*S
#define N_DIM 2048
#define K_DIM 2048

typedef __bf16 bf16x8_t __attribute__((ext_vector_type(8)));
typedef float f32x4_t __attribute__((ext_vector_type(4)));

// ---------------- threefry2x32, JAX partitionable path, key=(0,1) -------------
// bits(j) = o0^o1 of threefry2x32(key=(0,1), ctr=(0, j)); keep iff bits < 0xC0000000.
// Verified round 1: absmax 0.0625 -> mask exact.
__device__ __forceinline__ unsigned tf_rotl(unsigned x, int r) {
  return (x << r) | (x >> (32 - r));
}
__device__ __forceinline__ unsigned threefry_mask_bits(unsigned ctr) {
  unsigned x0 = 0u, x1 = ctr;
  const unsigned ks0 = 0u, ks1 = 1u, ks2 = 0x1BD11BDBu;
  x0 += ks0; x1 += ks1;
#define TFR(r) { x0 += x1; x1 = tf_rotl(x1, (r)); x1 ^= x0; }
  TFR(13) TFR(15) TFR(26) TFR(6)
  x0 += ks1; x1 += ks2 + 1u;
  TFR(17) TFR(29) TFR(16) TFR(24)
  x0 += ks2; x1 += ks0 + 2u;
  TFR(13) TFR(15) TFR(26) TFR(6)
  x0 += ks0; x1 += ks1 + 3u;
  TFR(17) TFR(29) TFR(16) TFR(24)
  x0 += ks1; x1 += ks2 + 4u;
  TFR(13) TFR(15) TFR(26) TFR(6)
  x0 += ks2; x1 += ks0 + 5u;
#undef TFR
  return x0 ^ x1;
}

// ---------------- async global->LDS, 16B per lane -----------------------------
__device__ __forceinline__ void gload_lds16(const __hip_bfloat16* g, unsigned short* l) {
  __builtin_amdgcn_global_load_lds(
      (const __attribute__((address_space(1))) unsigned int*)g,
      (__attribute__((address_space(3))) unsigned int*)l,
      16, 0, 0);
}

// ---------------- W [K][N] fp32 -> Wt [N][K] bf16 -----------------------------
__global__ __launch_bounds__(256) void wt_kernel(
    const float* __restrict__ W1, const float* __restrict__ W2,
    __hip_bfloat16* __restrict__ W1t, __hip_bfloat16* __restrict__ W2t) {
  __shared__ float tile[32][33];
  const float* src = blockIdx.z ? W2 : W1;
  __hip_bfloat16* dst = blockIdx.z ? W2t : W1t;
  int x = blockIdx.x * 32 + threadIdx.x;
  int y = blockIdx.y * 32 + threadIdx.y;
#pragma unroll
  for (int i = 0; i < 32; i += 8)
    tile[threadIdx.y + i][threadIdx.x] = src[(size_t)(y + i) * N_DIM + x];
  __syncthreads();
  int xo = blockIdx.y * 32 + threadIdx.x;
  int yo = blockIdx.x * 32 + threadIdx.y;
#pragma unroll
  for (int i = 0; i < 32; i += 8)
    dst[(size_t)(yo + i) * K_DIM + xo] = __float2bfloat16(tile[threadIdx.x][threadIdx.y + i]);
}

// ---------------- LayerNorm (no affine) -> bf16 -------------------------------
__global__ __launch_bounds__(256) void ln_kernel(const float* __restrict__ X,
                                                 __hip_bfloat16* __restrict__ Xn) {
  const int row = blockIdx.x;
  const float4* xv = (const float4*)(X + (size_t)row * K_DIM);
  float4 v0 = xv[threadIdx.x];
  float4 v1 = xv[threadIdx.x + 256];
  float s  = v0.x + v0.y + v0.z + v0.w + v1.x + v1.y + v1.z + v1.w;
  float ss = v0.x*v0.x + v0.y*v0.y + v0.z*v0.z + v0.w*v0.w
           + v1.x*v1.x + v1.y*v1.y + v1.z*v1.z + v1.w*v1.w;
#pragma unroll
  for (int off = 32; off > 0; off >>= 1) {
    s  += __shfl_xor(s, off);
    ss += __shfl_xor(ss, off);
  }
  __shared__ float rs[4], rss[4];
  const int wave = threadIdx.x >> 6;
  if ((threadIdx.x & 63) == 0) { rs[wave] = s; rss[wave] = ss; }
  __syncthreads();
  float S  = rs[0] + rs[1] + rs[2] + rs[3];
  float SS = rss[0] + rss[1] + rss[2] + rss[3];
  float mean = S * (1.0f / 2048.0f);
  float var  = SS * (1.0f / 2048.0f) - mean * mean;
  float rstd = 1.0f / sqrtf(var + 1e-6f);
  float vv[8] = {v0.x, v0.y, v0.z, v0.w, v1.x, v1.y, v1.z, v1.w};
  unsigned short o[8];
#pragma unroll
  for (int i = 0; i < 8; i++) {
    __hip_bfloat16 b = __float2bfloat16((vv[i] - mean) * rstd);
    o[i] = *(unsigned short*)&b;
  }
  ushort4* dst = (ushort4*)(Xn + (size_t)row * K_DIM);
  dst[threadIdx.x]       = make_ushort4(o[0], o[1], o[2], o[3]);
  dst[threadIdx.x + 256] = make_ushort4(o[4], o[5], o[6], o[7]);
}

// ---------------- 128x128 MFMA GEMM, BK=64 dbuf, XOR-swizzled LDS -------------
// A[M][K], Bt[N][K] bf16. EPI=0: H=relu(A@B)->bf16. EPI=1: out=Xn+dropout/0.75.
// LDS rows are 64 elems (128 B). Slot (row, chunk c) holds global 16B-chunk
// c ^ (row&7): write-side source offset and read-side address are both static
// per lane, and consecutive 8-lane groups of ds_read_b128 hit all 8 bank-quads
// (conflict-free; unswizzled 128B rows would be 16-way conflicted).
// 32 barriers total (vs 64 at BK=32); prefetch covered by 32 MFMA per stage.
template <int EPI>
__global__ __launch_bounds__(256) void gemm128(
    const __hip_bfloat16* __restrict__ A,
    const __hip_bfloat16* __restrict__ Bt,
    const __hip_bfloat16* __restrict__ Xn,   // EPI=1 residual
    __hip_bfloat16* __restrict__ Hout,       // EPI=0 output
    float* __restrict__ Fout) {              // EPI=1 output
  __shared__ unsigned short As[2][128 * 64];  // 32 KB
  __shared__ unsigned short Bs[2][128 * 64];  // 32 KB
  const int tid  = threadIdx.x;
  const int lane = tid & 63;
  const int wave = tid >> 6;
  const int wm = wave >> 1, wn = wave & 1;
  // grid: x walks M (fastest) -> consecutive blocks share the B panel in L2.
  const int mBase = blockIdx.x * 128;
  const int nBase = blockIdx.y * 128;

  f32x4_t acc[4][4];
#pragma unroll
  for (int i = 0; i < 4; i++)
#pragma unroll
    for (int j = 0; j < 4; j++) acc[i][j] = (f32x4_t){0.f, 0.f, 0.f, 0.f};

  // ---- staging: 16 KB per matrix per stage = 16 chunks of 1 KB (8 rows x 128B).
  // wave w loads chunks {w, w+4, w+8, w+12} of A and of B (8 gloads/stage).
  // lane l covers row 8*ca + (l>>3), source k-chunk (l&7)^((l>>3)&7) (swizzle).
  const int rowIn  = lane >> 3;                       // 0..7 within chunk
  const int csrc   = ((lane & 7) ^ (rowIn & 7)) << 3; // swizzled src k-elem offset
  const __hip_bfloat16* aSrc[4];
  const __hip_bfloat16* bSrc[4];
  int sDst[4];
#pragma unroll
  for (int j = 0; j < 4; j++) {
    const int ca = wave + 4 * j;                      // chunk index 0..15
    aSrc[j] = A  + (size_t)(mBase + 8 * ca + rowIn) * K_DIM + csrc;
    bSrc[j] = Bt + (size_t)(nBase + 8 * ca + rowIn) * K_DIM + csrc;
    sDst[j] = ca * 512;                               // shorts: 1KB per chunk
  }

  // ---- fragment read addresses (static swizzle: row&7 == fr&7)
  const int fr = lane & 15;
  const int fq = lane >> 4;
  const int sw = fr & 7;
  const int cA0 = (fq ^ sw) * 8;          // kk=0 chunk offset (shorts)
  const int cA1 = ((4 | fq) ^ sw) * 8;    // kk=1 chunk offset
  const int rowOffA = (wm * 64 + fr) * 64;
  const int rowOffB = (wn * 64 + fr) * 64;

#define STAGE(buf, k0)                                        \
  {                                                           \
    _Pragma("unroll")                                         \
    for (int j = 0; j < 4; j++) {                             \
      gload_lds16(aSrc[j] + (k0), &As[buf][sDst[j]]);         \
      gload_lds16(bSrc[j] + (k0), &Bs[buf][sDst[j]]);         \
    }                                                         \
  }

#define COMPUTE_HALF(buf, cOff)                                                 \
  {                                                                             \
    bf16x8_t af[4], bfr[4];                                                     \
    _Pragma("unroll")                                                           \
    for (int i = 0; i < 4; i++) af[i]  = *(const bf16x8_t*)(&As[buf][rowOffA + i * 1024 + (cOff)]); \
    _Pragma("unroll")                                                           \
    for (int i = 0; i < 4; i++) bfr[i] = *(const bf16x8_t*)(&Bs[buf][rowOffB + i * 1024 + (cOff)]); \
    _Pragma("unroll")                                                           \
    for (int mi = 0; mi < 4; mi++)                                              \
      _Pragma("unroll")                                                         \
      for (int ni = 0; ni < 4; ni++)                                            \
        acc[mi][ni] = __builtin_amdgcn_mfma_f32_16x16x32_bf16(af[mi], bfr[ni], acc[mi][ni], 0, 0, 0); \
  }
#define COMPUTE(buf) { COMPUTE_HALF(buf, cA0) COMPUTE_HALF(buf, cA1) }

  STAGE(0, 0)
  for (int k0 = 0; k0 < K_DIM - 128; k0 += 128) {
    __syncthreads();            // publish buf0 (k0)
    STAGE(1, k0 + 64)           // in flight during buf0 compute
    COMPUTE(0)
    __syncthreads();            // publish buf1 (k0+64)
    STAGE(0, k0 + 128)          // in flight during buf1 compute
    COMPUTE(1)
  }
  // tail: buf0 holds K-128, buf1 gets K-64
  __syncthreads();
  STAGE(1, K_DIM - 64)
  COMPUTE(0)
  __syncthreads();
  COMPUTE(1)
#undef STAGE
#undef COMPUTE
#undef COMPUTE_HALF

  // epilogue: D row = fq*4 + reg, col = fr (m89-verified C/D layout)
  const int mRow = mBase + wm * 64;
  const int nCol = nBase + wn * 64;
#pragma unroll
  for (int mi = 0; mi < 4; mi++) {
#pragma unroll
    for (int ni = 0; ni < 4; ni++) {
      const int n  = nCol + ni * 16 + fr;
      const int m0 = mRow + mi * 16 + fq * 4;
#pragma unroll
      for (int r = 0; r < 4; r++) {
        float v = acc[mi][ni][r];
        size_t j = (size_t)(m0 + r) * N_DIM + n;
        if (EPI == 0) {
          Hout[j] = __float2bfloat16(fmaxf(v, 0.0f));
        } else {
          unsigned bits = threefry_mask_bits((unsigned)j);
          float y  = (bits < 0xC0000000u) ? v * (1.0f / 0.75f) : 0.0f;
          Fout[j]  = __bfloat162float(Xn[j]) + y;
        }
      }
    }
  }
}

extern "C" void kernel_launch(void* const* d_in, const int* in_sizes, int n_in,
                              void* d_out, int out_size, void* d_ws, size_t ws_size,
                              hipStream_t stream) {
  (void)in_sizes; (void)n_in; (void)out_size; (void)ws_size;
  const float* X  = (const float*)d_in[0];
  const float* W1 = (const float*)d_in[1];
  const float* W2 = (const float*)d_in[2];
  float* out = (float*)d_out;

  unsigned char* ws = (unsigned char*)d_ws;
  __hip_bfloat16* Xn  = (__hip_bfloat16*)(ws);                       // 32 MB
  __hip_bfloat16* H   = (__hip_bfloat16*)(ws + ((size_t)32 << 20));  // 32 MB
  __hip_bfloat16* W1t = (__hip_bfloat16*)(ws + ((size_t)64 << 20));  //  8 MB
  __hip_bfloat16* W2t = (__hip_bfloat16*)(ws + ((size_t)72 << 20));  //  8 MB

  wt_kernel<<<dim3(64, 64, 2), dim3(32, 8, 1), 0, stream>>>(W1, W2, W1t, W2t);
  ln_kernel<<<M_DIM, 256, 0, stream>>>(X, Xn);
  gemm128<0><<<dim3(M_DIM / 128, N_DIM / 128), 256, 0, stream>>>(Xn, W1t, nullptr, H, nullptr);
  gemm128<1><<<dim3(M_DIM / 128, N_DIM / 128), 256, 0, stream>>>(H, W2t, Xn, nullptr, out);
}